// Round 10
// baseline (139.203 us; speedup 1.0000x reference)
//
#include <hip/hip_runtime.h>
#include <math.h>

// FilterMLPBlock: out = LN_D( irfft(rfft(x,ortho)*w,ortho) + x ),  B=4096,S=64,D=256
// R10: occupancy push of R9 (132.8us, 16 waves/CU).
//   h = C2 * ((W+1) o (C1 * x))        [residual folded: C2*C1 = I]
//   GEMM1: K=128 hi/lo-split bf16 of x; GEMM2: K=64 plain-bf16 V.
// Changes vs R9: 512-thread blocks, 8 waves, N=32 d/wave -> acc 8 frags
// (32 AGPR) + ~45 arch = ~77 unified <= 85 cap at launch_bounds(512,6)
// -> 3 blocks/CU = 24 waves/CU (75%), per-wave chains halved.
// LN partials packed (bf16,bf16) in u32 [64][131] to fit the V-region overlay.

typedef __attribute__((ext_vector_type(8))) short short8;
typedef __attribute__((ext_vector_type(4))) float f32x4;
typedef __attribute__((ext_vector_type(4))) unsigned int u32x4;
typedef __attribute__((ext_vector_type(2))) unsigned int u32x2;

#define VROW 144   // V row stride bytes (64 bf16 + 16 pad), 16B-aligned b128

__device__ __forceinline__ unsigned short bf16rn(float v) {
    unsigned u = __float_as_uint(v);
    u += 0x7fffu + ((u >> 16) & 1u);
    return (unsigned short)(u >> 16);
}
__device__ __forceinline__ float bf16tof(unsigned short h) {
    return __uint_as_float(((unsigned)h) << 16);
}
__device__ __forceinline__ unsigned packsplit(float v) {
    unsigned short vh = bf16rn(v);
    float rem = v - bf16tof(vh);
    return (unsigned)vh | ((unsigned)bf16rn(rem) << 16);
}

// A tables in ws: A1 = 16 frags (K=128, hi/lo-duplicated C1 cols), 16 KB;
// A2 = 8 frags (K=64, C2 cols), 8 KB at short-offset 8192. (verbatim R9)
__global__ void pack_A_kernel(unsigned short* __restrict__ apack) {
    const int bid  = blockIdx.x;         // 0..23
    const int lane = threadIdx.x;        // 0..63
    const float step = 6.28318530717958647692f / 64.f;
    if (bid < 16) {                      // A1: frag = kt*4+mi
        const int kt = bid >> 2, mi = bid & 3;
        const int m = mi * 16 + (lane & 15);
        unsigned short* dst = apack + ((size_t)bid * 64 + lane) * 8;
        #pragma unroll
        for (int w = 0; w < 4; ++w) {
            const int c = 16 * kt + 4 * (lane >> 4) + w;    // time index t
            float val;
            if (m <= 32) val =  cosf(step * (float)((m * c) & 63)) * 0.125f;
            else         val = -sinf(step * (float)(((m - 32) * c) & 63)) * 0.125f;
            const unsigned short bb = bf16rn(val);
            dst[2 * w + 0] = bb;
            dst[2 * w + 1] = bb;
        }
    } else {                             // A2: frag = kt*4+mi, kt in 0..1
        const int fid = bid - 16;
        const int kt = fid >> 2, mi = fid & 3;
        const int m = mi * 16 + (lane & 15);
        unsigned short* dst = apack + 8192 + ((size_t)fid * 64 + lane) * 8;
        #pragma unroll
        for (int j = 0; j < 8; ++j) {
            const int c = kt * 32 + 8 * (lane >> 4) + j;    // V-row index
            float val;
            if (c == 0)       val = 0.125f;
            else if (c == 32) val = (m & 1) ? -0.125f : 0.125f;
            else if (c < 32)  val =  0.25f * cosf(step * (float)((c * m) & 63));
            else              val = -0.25f * sinf(step * (float)(((c - 32) * m) & 63));
            dst[j] = bf16rn(val);
        }
    }
}

#define MFMA(A, B, C) __builtin_amdgcn_mfma_f32_16x16x32_bf16( \
    __builtin_bit_cast(short8, A), (B), (C), 0, 0, 0)

__global__ __launch_bounds__(512, 6)
void fft_ln_kernel(const float* __restrict__ x,
                   const float* __restrict__ cw,
                   const float* __restrict__ gamma,
                   const float* __restrict__ beta,
                   const unsigned short* __restrict__ apack,
                   float* __restrict__ out) {
    __shared__ __align__(16) char smem[8 * 32 * VROW];  // 36.9 KB: V; LN overlays
    __shared__ float mr[128];                           // [64][2] mean, rstd
    const int tid = threadIdx.x, lane = tid & 63, wv = tid >> 6;  // wv 0..7
    const int hi = lane >> 4, lm = lane & 15;
    const int b = blockIdx.x, dbase = wv * 32;          // wave's 32-wide d-range
    const float* __restrict__ xb = x + (size_t)b * 16384;
    const u32x4* __restrict__ ap1 = (const u32x4*)apack;
    const u32x4* __restrict__ ap2 = (const u32x4*)(apack + 8192);

    f32x4 acc[8];                                       // [mi*2+ni]
    #pragma unroll
    for (int i = 0; i < 8; ++i) acc[i] = (f32x4)0.f;

    // ---- GEMM1: U = C1*x, K=128 hi/lo. A-frags streamed from global (L1-hot).
    #pragma unroll
    for (int kt = 0; kt < 4; ++kt) {
        const u32x4 af0 = ap1[(kt * 4 + 0) * 64 + lane];
        const u32x4 af1 = ap1[(kt * 4 + 1) * 64 + lane];
        const u32x4 af2 = ap1[(kt * 4 + 2) * 64 + lane];
        const u32x4 af3 = ap1[(kt * 4 + 3) * 64 + lane];
        const float* __restrict__ xp = xb + (16 * kt + 4 * hi) * 256 + dbase + lm;
        #pragma unroll
        for (int ni = 0; ni < 2; ++ni) {
            u32x4 bw;
            #pragma unroll
            for (int j = 0; j < 4; ++j) bw[j] = packsplit(xp[j * 256 + ni * 16]);
            const short8 bb = __builtin_bit_cast(short8, bw);
            acc[0 * 2 + ni] = MFMA(af0, bb, acc[0 * 2 + ni]);
            acc[1 * 2 + ni] = MFMA(af1, bb, acc[1 * 2 + ni]);
            acc[2 * 2 + ni] = MFMA(af2, bb, acc[2 * 2 + ni]);
            acc[3 * 2 + ni] = MFMA(af3, bb, acc[3 * 2 + ni]);
        }
    }

    // ---- filter multiply with residual fold: V = (W+1) o U (fp32, lane-local)
    #pragma unroll
    for (int mi = 0; mi < 2; ++mi)
    #pragma unroll
    for (int ni = 0; ni < 2; ++ni) {
        const int d = dbase + ni * 16 + lm;
        #pragma unroll
        for (int r = 0; r < 4; ++r) {
            const int f = mi * 16 + hi * 4 + r;
            const float2 wc = *(const float2*)(cw + ((size_t)(f * 256 + d)) * 2);
            const float wr1 = wc.x + 1.f;
            const float Ure = acc[mi * 2 + ni][r];
            const float Uim = acc[(mi + 2) * 2 + ni][r];
            float Vre = Ure * wr1 - Uim * wc.y;
            float Vim = Ure * wc.y + Uim * wr1;
            if (mi == 0 && r == 0) {                 // f==0 lanes: DC & Nyquist
                const float w32 = cw[(32 * 256 + d) * 2] + 1.f;
                if (hi == 0) { Vre = Ure * wr1; Vim = Uim * w32; }
            }
            acc[mi * 2 + ni][r]       = Vre;
            acc[(mi + 2) * 2 + ni][r] = Vim;
        }
    }

    // ---- V -> plain bf16 LDS table [dl][f], wave-private 4.5 KB, stride 144 B
    char* vb = smem + wv * 32 * VROW;
    #pragma unroll
    for (int mi = 0; mi < 4; ++mi)
    #pragma unroll
    for (int ni = 0; ni < 2; ++ni) {
        const f32x4 a4 = acc[mi * 2 + ni];
        u32x2 p;
        p[0] = (unsigned)bf16rn(a4[0]) | ((unsigned)bf16rn(a4[1]) << 16);
        p[1] = (unsigned)bf16rn(a4[2]) | ((unsigned)bf16rn(a4[3]) << 16);
        const int dl = ni * 16 + lm;
        *(u32x2*)(vb + dl * VROW + mi * 32 + hi * 8) = p;   // f0 = mi*16+hi*4
    }

    // ---- GEMM2: h = C2 * V, K=64 plain bf16 (acc regs reused, re-zeroed)
    #pragma unroll
    for (int i = 0; i < 8; ++i) acc[i] = (f32x4)0.f;
    #pragma unroll
    for (int kt = 0; kt < 2; ++kt) {
        const u32x4 af0 = ap2[(kt * 4 + 0) * 64 + lane];
        const u32x4 af1 = ap2[(kt * 4 + 1) * 64 + lane];
        const u32x4 af2 = ap2[(kt * 4 + 2) * 64 + lane];
        const u32x4 af3 = ap2[(kt * 4 + 3) * 64 + lane];
        #pragma unroll
        for (int ni = 0; ni < 2; ++ni) {
            const int dl = ni * 16 + lm;
            const u32x4 bw = *(const u32x4*)(vb + dl * VROW + kt * 64 + hi * 16);
            const short8 bb = __builtin_bit_cast(short8, bw);
            acc[0 * 2 + ni] = MFMA(af0, bb, acc[0 * 2 + ni]);
            acc[1 * 2 + ni] = MFMA(af1, bb, acc[1 * 2 + ni]);
            acc[2 * 2 + ni] = MFMA(af2, bb, acc[2 * 2 + ni]);
            acc[3 * 2 + ni] = MFMA(af3, bb, acc[3 * 2 + ni]);
        }
    }

    // ---- LayerNorm over d: packed (bf16,bf16) partials [64][131] u32 overlay
    __syncthreads();                       // all waves done reading their V
    unsigned* pp = (unsigned*)smem;        // [64 rows][131], 33.5 KB <= 36.9 KB
    #pragma unroll
    for (int mi = 0; mi < 4; ++mi)
    #pragma unroll
    for (int r = 0; r < 4; ++r) {
        const float v0 = acc[mi * 2 + 0][r];
        const float v1 = acc[mi * 2 + 1][r];
        const float s1 = v0 + v1;
        const float s2 = fmaf(v0, v0, v1 * v1);
        const int row = mi * 16 + hi * 4 + r;
        pp[row * 131 + wv * 16 + lm] =
            (unsigned)bf16rn(s1) | ((unsigned)bf16rn(s2) << 16);
    }
    __syncthreads();
    if (tid < 64) {
        float s1 = 0.f, s2 = 0.f;
        #pragma unroll
        for (int j = 0; j < 128; ++j) {
            const unsigned v = pp[tid * 131 + j];
            s1 += bf16tof((unsigned short)(v & 0xffffu));
            s2 += bf16tof((unsigned short)(v >> 16));
        }
        const float mean = s1 * (1.f / 256.f);
        const float var  = s2 * (1.f / 256.f) - mean * mean;
        mr[tid * 2 + 0] = mean;
        mr[tid * 2 + 1] = rsqrtf(var + 1e-12f);
    }
    __syncthreads();

    // ---- normalize + affine + store (64B segments per 16-lane group)
    float gv[2], bv[2];
    #pragma unroll
    for (int ni = 0; ni < 2; ++ni) {
        gv[ni] = gamma[dbase + ni * 16 + lm];
        bv[ni] = beta [dbase + ni * 16 + lm];
    }
    float* __restrict__ ob = out + (size_t)b * 16384;
    #pragma unroll
    for (int mi = 0; mi < 4; ++mi)
    #pragma unroll
    for (int r = 0; r < 4; ++r) {
        const int row = mi * 16 + hi * 4 + r;
        const float m  = mr[row * 2 + 0];
        const float rs = mr[row * 2 + 1];
        #pragma unroll
        for (int ni = 0; ni < 2; ++ni)
            ob[row * 256 + dbase + ni * 16 + lm] =
                (acc[mi * 2 + ni][r] - m) * rs * gv[ni] + bv[ni];
    }
}

extern "C" void kernel_launch(void* const* d_in, const int* in_sizes, int n_in,
                              void* d_out, int out_size, void* d_ws, size_t ws_size,
                              hipStream_t stream) {
    const float* x     = (const float*)d_in[0];
    const float* cw    = (const float*)d_in[1];   // [1,33,256,2]
    const float* gamma = (const float*)d_in[2];
    const float* beta  = (const float*)d_in[3];
    float* outp = (float*)d_out;
    unsigned short* apack = (unsigned short*)d_ws;   // 24 KB fragment tables

    pack_A_kernel<<<24, 64, 0, stream>>>(apack);
    fft_ln_kernel<<<4096, 512, 0, stream>>>(x, cw, gamma, beta, apack, outp);
}

// Round 11
// 129.972 us; speedup vs baseline: 1.0710x; 1.0710x over previous
//
#include <hip/hip_runtime.h>
#include <math.h>

// FilterMLPBlock: out = LN_D( irfft(rfft(x,ortho)*w,ortho) + x ),  B=4096,S=64,D=256
// R11 = R9 geometry (132.8us) + precision re-budget + hardware bf16 cvt.
//   h = C2 * ((W+1) o (C1 * x))        [residual folded: C2*C1 = I]
//   GEMM1: K=64 plain-bf16 x (was K=128 hi/lo)  -> 32 MFMA, A1 table 8 KB
//   GEMM2: K=64 plain-bf16 V (unchanged)        -> 32 MFMA
//   All f32->bf16 packing via v_cvt_pk_bf16_f32 (1 instr / 2 floats, RNE).
// R10 post-mortem: narrow waves amortize worse (A-loads, LN cols) -> back to
// 4 waves x N=64. VALU was ~48us of hand bit-twiddled packing; this round cuts
// pack cost ~10x and halves GEMM1. Error budget: +x-bf16 ~0.02-0.03 on top of
// 0.031 -> ~0.05 expected (threshold 0.12).

typedef __attribute__((ext_vector_type(8))) short short8;
typedef __attribute__((ext_vector_type(4))) float f32x4;
typedef __attribute__((ext_vector_type(4))) unsigned int u32x4;
typedef __attribute__((ext_vector_type(2))) unsigned int u32x2;

#define VROW 144   // V row stride bytes (64 bf16 + 16 pad), 16B-aligned b128

__device__ __forceinline__ unsigned short bf16rn(float v) {
    unsigned u = __float_as_uint(v);
    u += 0x7fffu + ((u >> 16) & 1u);
    return (unsigned short)(u >> 16);
}
// hardware packed convert: dst = (bf16(a) in lo16, bf16(b) in hi16), RNE
__device__ __forceinline__ unsigned cvtpk(float a, float b) {
    unsigned r;
    asm("v_cvt_pk_bf16_f32 %0, %1, %2" : "=v"(r) : "v"(a), "v"(b));
    return r;
}

// A tables in ws: A1 = 8 frags (K=64, C1), 8 KB; A2 = 8 frags (K=64, C2),
// 8 KB at short-offset 4096. Frag layout (HW-verified by R8/R9 passing):
// lane l, j=0..7: m = mi*16 + (l&15), k = kt*32 + 8*(l>>4) + j.
__global__ void pack_A_kernel(unsigned short* __restrict__ apack) {
    const int bid  = blockIdx.x;         // 0..15
    const int lane = threadIdx.x;        // 0..63
    const float step = 6.28318530717958647692f / 64.f;
    const int fid = bid & 7;
    const int kt = fid >> 2, mi = fid & 3;
    const int m = mi * 16 + (lane & 15);
    if (bid < 8) {                       // A1 = C1 (rfft, ortho, re||im rows)
        unsigned short* dst = apack + ((size_t)fid * 64 + lane) * 8;
        #pragma unroll
        for (int j = 0; j < 8; ++j) {
            const int t = kt * 32 + 8 * (lane >> 4) + j;    // time index
            float val;
            if (m <= 32) val =  cosf(step * (float)((m * t) & 63)) * 0.125f;
            else         val = -sinf(step * (float)(((m - 32) * t) & 63)) * 0.125f;
            dst[j] = bf16rn(val);
        }
    } else {                             // A2 = C2 (irfft, ortho)
        unsigned short* dst = apack + 4096 + ((size_t)fid * 64 + lane) * 8;
        #pragma unroll
        for (int j = 0; j < 8; ++j) {
            const int c = kt * 32 + 8 * (lane >> 4) + j;    // V-row index
            float val;
            if (c == 0)       val = 0.125f;
            else if (c == 32) val = (m & 1) ? -0.125f : 0.125f;
            else if (c < 32)  val =  0.25f * cosf(step * (float)((c * m) & 63));
            else              val = -0.25f * sinf(step * (float)(((c - 32) * m) & 63));
            dst[j] = bf16rn(val);
        }
    }
}

#define MFMA(A, B, C) __builtin_amdgcn_mfma_f32_16x16x32_bf16( \
    __builtin_bit_cast(short8, A), (B), (C), 0, 0, 0)

__global__ __launch_bounds__(256, 4)
void fft_ln_kernel(const float* __restrict__ x,
                   const float* __restrict__ cw,
                   const float* __restrict__ gamma,
                   const float* __restrict__ beta,
                   const unsigned short* __restrict__ apack,
                   float* __restrict__ out) {
    __shared__ __align__(16) char smem[4 * 64 * VROW];  // 36.9 KB: V; LN overlays
    __shared__ float mr[128];                           // [64][2] mean, rstd
    const int tid = threadIdx.x, lane = tid & 63, wv = tid >> 6;
    const int hi = lane >> 4, lm = lane & 15;
    const int b = blockIdx.x, dbase = wv * 64;
    const float* __restrict__ xb = x + (size_t)b * 16384;
    const u32x4* __restrict__ ap1 = (const u32x4*)apack;
    const u32x4* __restrict__ ap2 = (const u32x4*)(apack + 4096);

    f32x4 acc[16];                       // [mi*4+ni]
    #pragma unroll
    for (int i = 0; i < 16; ++i) acc[i] = (f32x4)0.f;

    // ---- GEMM1: U = C1*x, K=64 plain bf16. x packed by v_cvt_pk (RNE). ----
    #pragma unroll
    for (int kt = 0; kt < 2; ++kt) {
        const u32x4 af0 = ap1[(kt * 4 + 0) * 64 + lane];
        const u32x4 af1 = ap1[(kt * 4 + 1) * 64 + lane];
        const u32x4 af2 = ap1[(kt * 4 + 2) * 64 + lane];
        const u32x4 af3 = ap1[(kt * 4 + 3) * 64 + lane];
        const float* __restrict__ xp = xb + (kt * 32 + 8 * hi) * 256 + dbase + lm;
        #pragma unroll
        for (int ni = 0; ni < 4; ++ni) {
            float xv[8];
            #pragma unroll
            for (int j = 0; j < 8; ++j) xv[j] = xp[j * 256 + ni * 16];
            u32x4 bw;
            bw[0] = cvtpk(xv[0], xv[1]);
            bw[1] = cvtpk(xv[2], xv[3]);
            bw[2] = cvtpk(xv[4], xv[5]);
            bw[3] = cvtpk(xv[6], xv[7]);
            const short8 bb = __builtin_bit_cast(short8, bw);
            acc[0 * 4 + ni] = MFMA(af0, bb, acc[0 * 4 + ni]);
            acc[1 * 4 + ni] = MFMA(af1, bb, acc[1 * 4 + ni]);
            acc[2 * 4 + ni] = MFMA(af2, bb, acc[2 * 4 + ni]);
            acc[3 * 4 + ni] = MFMA(af3, bb, acc[3 * 4 + ni]);
        }
    }

    // ---- filter multiply with residual fold: V = (W+1) o U (fp32, lane-local)
    #pragma unroll
    for (int mi = 0; mi < 2; ++mi)
    #pragma unroll
    for (int ni = 0; ni < 4; ++ni) {
        const int d = dbase + ni * 16 + lm;
        #pragma unroll
        for (int r = 0; r < 4; ++r) {
            const int f = mi * 16 + hi * 4 + r;
            const float2 wc = *(const float2*)(cw + ((size_t)(f * 256 + d)) * 2);
            const float wr1 = wc.x + 1.f;
            const float Ure = acc[mi * 4 + ni][r];
            const float Uim = acc[(mi + 2) * 4 + ni][r];
            float Vre = Ure * wr1 - Uim * wc.y;
            float Vim = Ure * wc.y + Uim * wr1;
            if (mi == 0 && r == 0) {                 // f==0 lanes: DC & Nyquist
                const float w32 = cw[(32 * 256 + d) * 2] + 1.f;
                if (hi == 0) { Vre = Ure * wr1; Vim = Uim * w32; }
            }
            acc[mi * 4 + ni][r]       = Vre;
            acc[(mi + 2) * 4 + ni][r] = Vim;
        }
    }

    // ---- V -> bf16 LDS table [dl][f] via cvt_pk, wave-private, stride 144 B
    char* vb = smem + wv * 64 * VROW;
    #pragma unroll
    for (int mi = 0; mi < 4; ++mi)
    #pragma unroll
    for (int ni = 0; ni < 4; ++ni) {
        const f32x4 a4 = acc[mi * 4 + ni];
        u32x2 p;
        p[0] = cvtpk(a4[0], a4[1]);
        p[1] = cvtpk(a4[2], a4[3]);
        const int dl = ni * 16 + lm;
        *(u32x2*)(vb + dl * VROW + mi * 32 + hi * 8) = p;   // f0 = mi*16+hi*4
    }

    // ---- GEMM2: h = C2 * V, K=64 plain bf16 (acc regs reused, re-zeroed)
    #pragma unroll
    for (int i = 0; i < 16; ++i) acc[i] = (f32x4)0.f;
    #pragma unroll
    for (int kt = 0; kt < 2; ++kt) {
        const u32x4 af0 = ap2[(kt * 4 + 0) * 64 + lane];
        const u32x4 af1 = ap2[(kt * 4 + 1) * 64 + lane];
        const u32x4 af2 = ap2[(kt * 4 + 2) * 64 + lane];
        const u32x4 af3 = ap2[(kt * 4 + 3) * 64 + lane];
        #pragma unroll
        for (int ni = 0; ni < 4; ++ni) {
            const int dl = ni * 16 + lm;
            const u32x4 bw = *(const u32x4*)(vb + dl * VROW + kt * 64 + hi * 16);
            const short8 bb = __builtin_bit_cast(short8, bw);
            acc[0 * 4 + ni] = MFMA(af0, bb, acc[0 * 4 + ni]);
            acc[1 * 4 + ni] = MFMA(af1, bb, acc[1 * 4 + ni]);
            acc[2 * 4 + ni] = MFMA(af2, bb, acc[2 * 4 + ni]);
            acc[3 * 4 + ni] = MFMA(af3, bb, acc[3 * 4 + ni]);
        }
    }

    // ---- LayerNorm over d: fp32 partials [64][66] overlay the V region ----
    __syncthreads();                       // all waves done reading their V
    float* psum = (float*)smem;            // [64][66]
    float* psq  = (float*)smem + 64 * 66;  // 33.8 KB <= 36.9 KB
    #pragma unroll
    for (int mi = 0; mi < 4; ++mi)
    #pragma unroll
    for (int r = 0; r < 4; ++r) {
        float s1 = 0.f, s2 = 0.f;
        #pragma unroll
        for (int ni = 0; ni < 4; ++ni) {
            const float v = acc[mi * 4 + ni][r];
            s1 += v;
            s2 = fmaf(v, v, s2);
        }
        const int row = mi * 16 + hi * 4 + r;
        psum[row * 66 + wv * 16 + lm] = s1;
        psq [row * 66 + wv * 16 + lm] = s2;
    }
    __syncthreads();
    if (tid < 64) {
        float s1 = 0.f, s2 = 0.f;
        #pragma unroll
        for (int j = 0; j < 64; ++j) {
            s1 += psum[tid * 66 + j];
            s2 += psq [tid * 66 + j];
        }
        const float mean = s1 * (1.f / 256.f);
        const float var  = s2 * (1.f / 256.f) - mean * mean;
        mr[tid * 2 + 0] = mean;
        mr[tid * 2 + 1] = rsqrtf(var + 1e-12f);
    }
    __syncthreads();

    // ---- normalize + affine + store (64B segments per 16-lane group) ----
    f32x4 gv, bv;
    #pragma unroll
    for (int ni = 0; ni < 4; ++ni) {
        gv[ni] = gamma[dbase + ni * 16 + lm];
        bv[ni] = beta [dbase + ni * 16 + lm];
    }
    float* __restrict__ ob = out + (size_t)b * 16384;
    #pragma unroll
    for (int mi = 0; mi < 4; ++mi)
    #pragma unroll
    for (int r = 0; r < 4; ++r) {
        const int row = mi * 16 + hi * 4 + r;
        const float m  = mr[row * 2 + 0];
        const float rs = mr[row * 2 + 1];
        #pragma unroll
        for (int ni = 0; ni < 4; ++ni)
            ob[row * 256 + dbase + ni * 16 + lm] =
                (acc[mi * 4 + ni][r] - m) * rs * gv[ni] + bv[ni];
    }
}

extern "C" void kernel_launch(void* const* d_in, const int* in_sizes, int n_in,
                              void* d_out, int out_size, void* d_ws, size_t ws_size,
                              hipStream_t stream) {
    const float* x     = (const float*)d_in[0];
    const float* cw    = (const float*)d_in[1];   // [1,33,256,2]
    const float* gamma = (const float*)d_in[2];
    const float* beta  = (const float*)d_in[3];
    float* outp = (float*)d_out;
    unsigned short* apack = (unsigned short*)d_ws;   // 16 KB fragment tables

    pack_A_kernel<<<16, 64, 0, stream>>>(apack);
    fft_ln_kernel<<<4096, 256, 0, stream>>>(x, cw, gamma, beta, apack, outp);
}